// Round 1
// baseline (1117.773 us; speedup 1.0000x reference)
//
#include <hip/hip_runtime.h>
#include <cstdint>
#include <cmath>

typedef _Float16 f16;
typedef _Float16 f16x8 __attribute__((ext_vector_type(8)));
typedef float f32x4 __attribute__((ext_vector_type(4)));

#define DEVI static __device__ __forceinline__

constexpr int B_ = 1024, S_ = 512, H_ = 2048, R_ = 64, G_ = 16, L_ = 4, A_ = 256;
constexpr float ADAPT = 0.1f;

// async global->LDS, 16B per lane. Dest is wave-uniform base + lane*16 (HW).
DEVI void gl_lds16(const void* g, void* l) {
  __builtin_amdgcn_global_load_lds((const __attribute__((address_space(1))) void*)g,
                                   (__attribute__((address_space(3))) void*)l,
                                   16, 0, 0);
}

__global__ void cvt_f16_kernel(const float* __restrict__ src, f16* __restrict__ dst, int n) {
  int i = blockIdx.x * blockDim.x + threadIdx.x;
  if (i < n) dst[i] = (f16)src[i];
}

// src [rows][cols] fp32 -> dst [cols][rows] f16 (×scale), batched over blockIdx.z.
// All dims used are multiples of 32, so no guards needed.
__global__ void transpose_cvt_kernel(const float* __restrict__ src, f16* __restrict__ dst,
                                     int rows, int cols, float scale) {
  src += (size_t)blockIdx.z * rows * cols;
  dst += (size_t)blockIdx.z * rows * cols;
  __shared__ float tile[32][33];
  const int tx = threadIdx.x, ty = threadIdx.y;
  const int r0 = blockIdx.y * 32, c0 = blockIdx.x * 32;
  #pragma unroll
  for (int i = ty; i < 32; i += 8)
    tile[i][tx] = src[(size_t)(r0 + i) * cols + (c0 + tx)];
  __syncthreads();
  #pragma unroll
  for (int i = ty; i < 32; i += 8)
    dst[(size_t)(c0 + i) * rows + (r0 + tx)] = (f16)(tile[tx][i] * scale);
}

enum { EPI_IN = 0, EPI_Z1 = 1, EPI_MAIN = 2, EPI_OUT = 3 };

// GEMM: out[M,N] = A[M,K1] * Bw^T  (Bw stored [N][K1])  (+ concat-K2: A2[M,K2] * B2w^T)
// m97 structure: BK=32, global_load_lds x16B, linear LDS, 16x16x32 f16 MFMA.
template <int BM, int BN, int WM, int WN, int EPI>
__global__ __launch_bounds__((BM / WM) * (BN / WN) * 64)
void gemm_f16_kernel(const f16* __restrict__ A, long long lda, long long Az,
                     const f16* __restrict__ Bw, long long ldb, long long Bz,
                     const f16* __restrict__ A2, long long lda2,
                     const f16* __restrict__ B2w, long long ldb2, long long B2z,
                     int NT1, int NT2,
                     const float* __restrict__ bias1, long long b1z,
                     const float* __restrict__ bias2, long long b2z,
                     void* __restrict__ outp, long long out_z, long long ldo,
                     int rows_per_group) {
  constexpr int NW = (BM / WM) * (BN / WN);   // waves per block
  constexpr int FM = WM / 16, FN = WN / 16;   // 16x16 frags per wave
  constexpr int RA = BM / (NW * 16), RB = BN / (NW * 16); // staging rounds
  const int tid = threadIdx.x, lane = tid & 63, wid = tid >> 6;
  const int bm0 = blockIdx.x * BM, bn0 = blockIdx.y * BN;
  const int z = blockIdx.z;
  A += (long long)z * Az;
  Bw += (long long)z * Bz;
  bias1 += (long long)z * b1z;
  const int gidx = (rows_per_group > 0) ? (bm0 / rows_per_group) : 0;
  if (B2w) B2w += (long long)gidx * B2z;
  if (bias2) bias2 += (long long)gidx * b2z;

  __shared__ __align__(16) f16 As[BM * 32];
  __shared__ __align__(16) f16 Bs[BN * 32];

  const int wm0 = (wid / (BN / WN)) * WM;
  const int wn0 = (wid % (BN / WN)) * WN;
  const int srow = wid * 16 + (lane >> 2);  // staging row within a round
  const int scol = (lane & 3) * 8;          // staging col (f16 elems)
  const int fr = lane & 15, fq = lane >> 4;

  f32x4 acc[FM][FN] = {};

  const int NT = NT1 + NT2;
  for (int kt = 0; kt < NT; ++kt) {
    const f16 *sA, *sB;
    long long ldA_, ldB_;
    int kk;
    if (kt < NT1) { sA = A;  ldA_ = lda;  sB = Bw;  ldB_ = ldb;  kk = kt * 32; }
    else          { sA = A2; ldA_ = lda2; sB = B2w; ldB_ = ldb2; kk = (kt - NT1) * 32; }
    #pragma unroll
    for (int r = 0; r < RA; ++r)
      gl_lds16(sA + (long long)(bm0 + r * NW * 16 + srow) * ldA_ + kk + scol,
               &As[(r * NW + wid) * 512]);
    #pragma unroll
    for (int r = 0; r < RB; ++r)
      gl_lds16(sB + (long long)(bn0 + r * NW * 16 + srow) * ldB_ + kk + scol,
               &Bs[(r * NW + wid) * 512]);
    __syncthreads();   // compiler drains vmcnt before s_barrier

    f16x8 af[FM], bf[FN];
    #pragma unroll
    for (int i = 0; i < FM; ++i)
      af[i] = *(const f16x8*)&As[(wm0 + i * 16 + fr) * 32 + fq * 8];
    #pragma unroll
    for (int j = 0; j < FN; ++j)
      bf[j] = *(const f16x8*)&Bs[(wn0 + j * 16 + fr) * 32 + fq * 8];
    #pragma unroll
    for (int i = 0; i < FM; ++i)
      #pragma unroll
      for (int j = 0; j < FN; ++j)
        acc[i][j] = __builtin_amdgcn_mfma_f32_16x16x32_f16(af[i], bf[j], acc[i][j], 0, 0, 0);
    __syncthreads();
  }

  // Epilogue. C/D layout (HW-verified): col = lane&15, row = (lane>>4)*4 + r.
  #pragma unroll
  for (int i = 0; i < FM; ++i) {
    #pragma unroll
    for (int j = 0; j < FN; ++j) {
      const int col = bn0 + wn0 + j * 16 + fr;
      const float b1 = bias1[col];
      const float b2v = bias2 ? ADAPT * bias2[col] : 0.f;
      #pragma unroll
      for (int r = 0; r < 4; ++r) {
        const int row = bm0 + wm0 + i * 16 + fq * 4 + r;
        float v = acc[i][j][r] + b1 + b2v;
        if constexpr (EPI == EPI_MAIN) {
          v = v > 0.f ? v : expm1f(v);   // ELU(alpha=1)
          ((f16*)outp)[(long long)row * ldo + col] = (f16)v;
        } else if constexpr (EPI == EPI_Z1) {
          ((f16*)outp)[(long long)z * out_z + (long long)row * ldo + col] = (f16)v;
        } else if constexpr (EPI == EPI_IN) {
          const f16 hv = (f16)v;
          #pragma unroll
          for (int g = 0; g < G_; ++g)   // broadcast across groups (group-major layout)
            ((f16*)outp)[(long long)g * B_ * H_ + (long long)row * ldo + col] = hv;
        } else {  // EPI_OUT: group-major row -> [B, G, A] fp32
          const int g = row >> 10, b = row & 1023;
          ((float*)outp)[((long long)b * G_ + g) * A_ + col] = v;
        }
      }
    }
  }
}

extern "C" void kernel_launch(void* const* d_in, const int* in_sizes, int n_in,
                              void* d_out, int out_size, void* d_ws, size_t ws_size,
                              hipStream_t stream) {
  const float* s      = (const float*)d_in[0];
  const float* W_in   = (const float*)d_in[1];
  const float* b_in   = (const float*)d_in[2];
  const float* W_main = (const float*)d_in[3];
  const float* b_main = (const float*)d_in[4];
  const float* Wa     = (const float*)d_in[5];
  const float* ba     = (const float*)d_in[6];
  const float* Wb     = (const float*)d_in[7];
  const float* bb     = (const float*)d_in[8];
  const float* W_out  = (const float*)d_in[9];
  const float* b_out  = (const float*)d_in[10];

  char* ws = (char*)d_ws;
  size_t off = 0;
  auto alloc = [&](size_t bytes) -> void* {
    void* p = ws + off;
    off += (bytes + 255) & ~(size_t)255;
    return p;
  };
  f16* sh   = (f16*)alloc((size_t)B_ * S_ * 2);            // s in f16           [1024][512]
  f16* Wint = (f16*)alloc((size_t)H_ * S_ * 2);            // W_in^T             [2048][512]
  f16* Wmt  = (f16*)alloc((size_t)L_ * H_ * H_ * 2);       // W_main^T per layer [2048][2048]
  f16* Wat  = (f16*)alloc((size_t)L_ * G_ * R_ * H_ * 2);  // Wa^T per (l,g)     [64][2048]
  f16* Wbt  = (f16*)alloc((size_t)L_ * G_ * H_ * R_ * 2);  // 0.1*Wb^T per (l,g) [2048][64]
  f16* Wot  = (f16*)alloc((size_t)A_ * H_ * 2);            // W_out^T            [256][2048]
  f16* xh0  = (f16*)alloc((size_t)G_ * B_ * H_ * 2);       // activations, group-major
  f16* xh1  = (f16*)alloc((size_t)G_ * B_ * H_ * 2);
  f16* z1h  = (f16*)alloc((size_t)G_ * B_ * R_ * 2);       // adapter mid        [16384][64]
  // total ~208 MB of d_ws

  // --- weight/input conversion (per call; deterministic) ---
  cvt_f16_kernel<<<(B_ * S_ + 255) / 256, 256, 0, stream>>>(s, sh, B_ * S_);
  dim3 tb(32, 8);
  transpose_cvt_kernel<<<dim3(H_ / 32, S_ / 32, 1),   tb, 0, stream>>>(W_in,   Wint, S_, H_, 1.f);
  transpose_cvt_kernel<<<dim3(H_ / 32, H_ / 32, L_),  tb, 0, stream>>>(W_main, Wmt,  H_, H_, 1.f);
  transpose_cvt_kernel<<<dim3(R_ / 32, H_ / 32, L_ * G_), tb, 0, stream>>>(Wa, Wat, H_, R_, 1.f);
  transpose_cvt_kernel<<<dim3(H_ / 32, R_ / 32, L_ * G_), tb, 0, stream>>>(Wb, Wbt, R_, H_, ADAPT);
  transpose_cvt_kernel<<<dim3(A_ / 32, H_ / 32, 1),   tb, 0, stream>>>(W_out,  Wot,  H_, A_, 1.f);

  // --- input layer: x0 = s @ W_in + b_in, broadcast to all G group slots ---
  gemm_f16_kernel<128, 128, 64, 64, EPI_IN><<<dim3(B_ / 128, H_ / 128, 1), 256, 0, stream>>>(
      sh, S_, 0, Wint, S_, 0,
      nullptr, 0, nullptr, 0, 0,
      S_ / 32, 0,
      b_in, 0, nullptr, 0,
      xh0, 0, H_, 0);

  f16* cur = xh0;
  f16* nxt = xh1;
  for (int l = 0; l < L_; ++l) {
    // z1[g] = x[g] @ Wa[l,g] + ba[l,g]   (grouped over blockIdx.z)
    gemm_f16_kernel<128, 64, 64, 32, EPI_Z1><<<dim3(B_ / 128, 1, G_), 256, 0, stream>>>(
        cur, H_, (long long)B_ * H_,
        Wat + (size_t)l * G_ * R_ * H_, H_, (long long)R_ * H_,
        nullptr, 0, nullptr, 0, 0,
        H_ / 32, 0,
        ba + (size_t)l * G_ * R_, R_, nullptr, 0,
        z1h, (long long)B_ * R_, R_, 0);
    // x_next = elu( x @ W_main[l] + b_main[l] + z1 @ (0.1*Wb[l,g]) + 0.1*bb[l,g] )
    // z2 fused via concat-K (last 2 K-steps read z1h / Wbt[g])
    gemm_f16_kernel<128, 128, 64, 64, EPI_MAIN><<<dim3(G_ * B_ / 128, H_ / 128, 1), 256, 0, stream>>>(
        cur, H_, 0,
        Wmt + (size_t)l * H_ * H_, H_, 0,
        z1h, R_,
        Wbt + (size_t)l * G_ * H_ * R_, R_, (long long)H_ * R_,
        H_ / 32, R_ / 32,
        b_main + (size_t)l * H_, 0,
        bb + (size_t)l * G_ * H_, H_,
        nxt, 0, H_, B_);
    f16* t = cur; cur = nxt; nxt = t;
  }

  // --- output: logits[b,g,:] = x @ W_out + b_out (fp32, permuted store) ---
  gemm_f16_kernel<128, 128, 64, 64, EPI_OUT><<<dim3(G_ * B_ / 128, A_ / 128, 1), 256, 0, stream>>>(
      cur, H_, 0, Wot, H_, 0,
      nullptr, 0, nullptr, 0, 0,
      H_ / 32, 0,
      b_out, 0, nullptr, 0,
      d_out, 0, A_, 0);
}

// Round 2
// 1009.003 us; speedup vs baseline: 1.1078x; 1.1078x over previous
//
#include <hip/hip_runtime.h>
#include <cstdint>
#include <cmath>

typedef _Float16 f16;
typedef _Float16 f16x8 __attribute__((ext_vector_type(8)));
typedef float f32x4 __attribute__((ext_vector_type(4)));

#define DEVI static __device__ __forceinline__

constexpr int B_ = 1024, S_ = 512, H_ = 2048, R_ = 64, G_ = 16, L_ = 4, A_ = 256;
constexpr float ADAPT = 0.1f;

// async global->LDS, 16B per lane. Dest is wave-uniform base + lane*16 (HW).
DEVI void gl_lds16(const void* g, void* l) {
  __builtin_amdgcn_global_load_lds((const __attribute__((address_space(1))) void*)g,
                                   (__attribute__((address_space(3))) void*)l,
                                   16, 0, 0);
}

__global__ void cvt_f16_kernel(const float* __restrict__ src, f16* __restrict__ dst, int n) {
  int i = blockIdx.x * blockDim.x + threadIdx.x;
  if (i < n) dst[i] = (f16)src[i];
}

// src [rows][cols] fp32 -> dst [cols][rows] f16 (×scale), batched over blockIdx.z.
__global__ void transpose_cvt_kernel(const float* __restrict__ src, f16* __restrict__ dst,
                                     int rows, int cols, float scale) {
  src += (size_t)blockIdx.z * rows * cols;
  dst += (size_t)blockIdx.z * rows * cols;
  __shared__ float tile[32][33];
  const int tx = threadIdx.x, ty = threadIdx.y;
  const int r0 = blockIdx.y * 32, c0 = blockIdx.x * 32;
  #pragma unroll
  for (int i = ty; i < 32; i += 8)
    tile[i][tx] = src[(size_t)(r0 + i) * cols + (c0 + tx)];
  __syncthreads();
  #pragma unroll
  for (int i = ty; i < 32; i += 8)
    dst[(size_t)(c0 + i) * rows + (r0 + tx)] = (f16)(tile[tx][i] * scale);
}

enum { EPI_Z1 = 0, EPI_MAIN = 1, EPI_OUT = 2, EPI_L0 = 3 };

// GEMM: out[M,N] = A[M,K1] * Bw^T (Bw stored [N][K1]) (+ concat-K2: A2[M,K2] * B2w^T)
// m97 structure: BK=32, global_load_lds x16B, linear LDS, 16x16x32 f16 MFMA.
// Loop split in two (no per-iteration source-select), incremental pointers.
template <int BM, int BN, int WM, int WN, int EPI>
__global__ __launch_bounds__((BM / WM) * (BN / WN) * 64)
void gemm_f16_kernel(const f16* __restrict__ A, long long lda, long long Az,
                     const f16* __restrict__ Bw, long long ldb, long long Bz,
                     const f16* __restrict__ A2, long long lda2,
                     const f16* __restrict__ B2w, long long ldb2, long long B2z,
                     int NT1, int NT2,
                     const float* __restrict__ bias1, long long b1z,
                     const float* __restrict__ bias2, long long b2z,
                     const f16* __restrict__ addmat,
                     void* __restrict__ outp, long long out_z, long long ldo,
                     int rows_per_group) {
  constexpr int NW = (BM / WM) * (BN / WN);   // waves per block
  constexpr int FM = WM / 16, FN = WN / 16;   // 16x16 frags per wave
  constexpr int RA = BM / (NW * 16), RB = BN / (NW * 16); // staging rounds
  const int tid = threadIdx.x, lane = tid & 63, wid = tid >> 6;
  const int bm0 = blockIdx.x * BM, bn0 = blockIdx.y * BN;
  const int z = blockIdx.z;
  const int gidx = (rows_per_group > 0) ? (bm0 / rows_per_group) : 0;

  __shared__ __align__(16) f16 As[BM * 32];
  __shared__ __align__(16) f16 Bs[BN * 32];

  const int wm0 = (wid / (BN / WN)) * WM;
  const int wn0 = (wid % (BN / WN)) * WN;
  const int srow = wid * 16 + (lane >> 2);  // staging row within a round
  const int scol = (lane & 3) * 8;          // staging col (f16 elems)
  const int fr = lane & 15, fq = lane >> 4;

  f32x4 acc[FM][FN] = {};

  const f16* arp = &As[(wm0 + fr) * 32 + fq * 8];
  const f16* brp = &Bs[(wn0 + fr) * 32 + fq * 8];
  auto compute = [&]() {
    f16x8 af[FM], bf[FN];
    #pragma unroll
    for (int i = 0; i < FM; ++i) af[i] = *(const f16x8*)(arp + i * 16 * 32);
    #pragma unroll
    for (int j = 0; j < FN; ++j) bf[j] = *(const f16x8*)(brp + j * 16 * 32);
    #pragma unroll
    for (int i = 0; i < FM; ++i)
      #pragma unroll
      for (int j = 0; j < FN; ++j)
        acc[i][j] = __builtin_amdgcn_mfma_f32_16x16x32_f16(af[i], bf[j], acc[i][j], 0, 0, 0);
  };

  if (NT1 > 0) {
    const f16* pa = A + (long long)z * Az + (long long)(bm0 + srow) * lda + scol;
    const f16* pb = Bw + (long long)z * Bz + (long long)(bn0 + srow) * ldb + scol;
    const long long stA = (long long)(NW * 16) * lda;
    const long long stB = (long long)(NW * 16) * ldb;
    for (int kt = 0; kt < NT1; ++kt) {
      #pragma unroll
      for (int r = 0; r < RA; ++r) gl_lds16(pa + r * stA, &As[(r * NW + wid) * 512]);
      #pragma unroll
      for (int r = 0; r < RB; ++r) gl_lds16(pb + r * stB, &Bs[(r * NW + wid) * 512]);
      pa += 32; pb += 32;
      __syncthreads();
      compute();
      __syncthreads();
    }
  }
  if (NT2 > 0) {
    const f16* pa = A2 + (long long)(bm0 + srow) * lda2 + scol;
    const f16* pb = B2w + (long long)gidx * B2z + (long long)(bn0 + srow) * ldb2 + scol;
    const long long stA = (long long)(NW * 16) * lda2;
    const long long stB = (long long)(NW * 16) * ldb2;
    for (int kt = 0; kt < NT2; ++kt) {
      #pragma unroll
      for (int r = 0; r < RA; ++r) gl_lds16(pa + r * stA, &As[(r * NW + wid) * 512]);
      #pragma unroll
      for (int r = 0; r < RB; ++r) gl_lds16(pb + r * stB, &Bs[(r * NW + wid) * 512]);
      pa += 32; pb += 32;
      __syncthreads();
      compute();
      __syncthreads();
    }
  }

  // Epilogue. C/D layout (HW-verified): col = lane&15, row = (lane>>4)*4 + r.
  const float* b1p = bias1 ? bias1 + (long long)z * b1z : nullptr;
  const float* b2p = bias2 ? bias2 + (long long)gidx * b2z : nullptr;
  #pragma unroll
  for (int i = 0; i < FM; ++i) {
    #pragma unroll
    for (int j = 0; j < FN; ++j) {
      const int col = bn0 + wn0 + j * 16 + fr;
      const float b1 = b1p ? b1p[col] : 0.f;
      const float b2v = b2p ? ADAPT * b2p[col] : 0.f;
      #pragma unroll
      for (int r = 0; r < 4; ++r) {
        const int row = bm0 + wm0 + i * 16 + fq * 4 + r;
        float v = acc[i][j][r] + b1 + b2v;
        if constexpr (EPI == EPI_MAIN) {
          v = v > 0.f ? v : expm1f(v);   // ELU(alpha=1)
          ((f16*)outp)[(long long)row * ldo + col] = (f16)v;
        } else if constexpr (EPI == EPI_L0) {
          v += (float)addmat[(long long)(row & (B_ - 1)) * H_ + col];
          v = v > 0.f ? v : expm1f(v);
          ((f16*)outp)[(long long)row * ldo + col] = (f16)v;
        } else if constexpr (EPI == EPI_Z1) {
          ((f16*)outp)[(long long)z * out_z + (long long)row * ldo + col] = (f16)v;
        } else {  // EPI_OUT: group-major row -> [B, G, A] fp32
          const int g = row >> 10, b = row & 1023;
          ((float*)outp)[((long long)b * G_ + g) * A_ + col] = v;
        }
      }
    }
  }
}

extern "C" void kernel_launch(void* const* d_in, const int* in_sizes, int n_in,
                              void* d_out, int out_size, void* d_ws, size_t ws_size,
                              hipStream_t stream) {
  const float* s      = (const float*)d_in[0];
  const float* W_in   = (const float*)d_in[1];
  const float* b_in   = (const float*)d_in[2];
  const float* W_main = (const float*)d_in[3];
  const float* b_main = (const float*)d_in[4];
  const float* Wa     = (const float*)d_in[5];
  const float* ba     = (const float*)d_in[6];
  const float* Wb     = (const float*)d_in[7];
  const float* bb     = (const float*)d_in[8];
  const float* W_out  = (const float*)d_in[9];
  const float* b_out  = (const float*)d_in[10];

  char* ws = (char*)d_ws;
  size_t off = 0;
  auto alloc = [&](size_t bytes) -> void* {
    void* p = ws + off;
    off += (bytes + 255) & ~(size_t)255;
    return p;
  };
  f16* sh   = (f16*)alloc((size_t)B_ * S_ * 2);            // s in f16           [1024][512]
  f16* Wint = (f16*)alloc((size_t)H_ * S_ * 2);            // W_in^T             [2048][512]
  f16* Wmt  = (f16*)alloc((size_t)L_ * H_ * H_ * 2);       // W_main^T per layer [2048][2048]
  f16* Wat  = (f16*)alloc((size_t)L_ * G_ * R_ * H_ * 2);  // Wa^T per (l,g)     [64][2048]
  f16* Wbt  = (f16*)alloc((size_t)L_ * G_ * H_ * R_ * 2);  // 0.1*Wb^T per (l,g) [2048][64]
  f16* Wot  = (f16*)alloc((size_t)A_ * H_ * 2);            // W_out^T            [256][2048]
  f16* xh0  = (f16*)alloc((size_t)G_ * B_ * H_ * 2);       // activations, group-major
  f16* xh1  = (f16*)alloc((size_t)G_ * B_ * H_ * 2);
  f16* z1h  = (f16*)alloc((size_t)G_ * B_ * R_ * 2);       // adapter mid        [16384][64]
  // x0 and y0 alias xh1's first 2*B*H slots: xh1 is first touched (written) by
  // the layer-1 main GEMM, which runs after x0/y0 are dead.
  f16* x0h  = xh1;                                         // x0 = s@W_in+b_in   [1024][2048]
  f16* y0h  = xh1 + (size_t)B_ * H_;                       // y0 = x0@Wm0+bm0    [1024][2048]

  // --- weight/input conversion (per call; deterministic) ---
  cvt_f16_kernel<<<(B_ * S_ + 255) / 256, 256, 0, stream>>>(s, sh, B_ * S_);
  dim3 tb(32, 8);
  transpose_cvt_kernel<<<dim3(H_ / 32, S_ / 32, 1),   tb, 0, stream>>>(W_in,   Wint, S_, H_, 1.f);
  transpose_cvt_kernel<<<dim3(H_ / 32, H_ / 32, L_),  tb, 0, stream>>>(W_main, Wmt,  H_, H_, 1.f);
  transpose_cvt_kernel<<<dim3(R_ / 32, H_ / 32, L_ * G_), tb, 0, stream>>>(Wa, Wat, H_, R_, 1.f);
  transpose_cvt_kernel<<<dim3(H_ / 32, R_ / 32, L_ * G_), tb, 0, stream>>>(Wb, Wbt, R_, H_, ADAPT);
  transpose_cvt_kernel<<<dim3(A_ / 32, H_ / 32, 1),   tb, 0, stream>>>(W_out,  Wot,  H_, A_, 1.f);

  // --- x0 = s @ W_in + b_in  [B, H] (single copy; group-invariant) ---
  gemm_f16_kernel<64, 128, 32, 64, EPI_Z1><<<dim3(B_ / 64, H_ / 128, 1), 256, 0, stream>>>(
      sh, S_, 0, Wint, S_, 0,
      nullptr, 0, nullptr, 0, 0,
      S_ / 32, 0,
      b_in, 0, nullptr, 0, nullptr,
      x0h, 0, H_, 0);

  // --- y0 = x0 @ W_main[0] + b_main[0]  [B, H] (group-invariant: 1/16 the work) ---
  gemm_f16_kernel<64, 128, 32, 64, EPI_Z1><<<dim3(B_ / 64, H_ / 128, 1), 256, 0, stream>>>(
      x0h, H_, 0, Wmt, H_, 0,
      nullptr, 0, nullptr, 0, 0,
      H_ / 32, 0,
      b_main, 0, nullptr, 0, nullptr,
      y0h, 0, H_, 0);

  // --- layer-0 z1[g] = x0 @ Wa[0,g] + ba[0,g]  (Az=0: shared x0) ---
  gemm_f16_kernel<64, 64, 32, 32, EPI_Z1><<<dim3(B_ / 64, 1, G_), 256, 0, stream>>>(
      x0h, H_, 0,
      Wat, H_, (long long)R_ * H_,
      nullptr, 0, nullptr, 0, 0,
      H_ / 32, 0,
      ba, R_, nullptr, 0, nullptr,
      z1h, (long long)B_ * R_, R_, 0);

  // --- layer-0 combine: x1 = elu(y0 + z1 @ (0.1*Wb[0,g]) + 0.1*bb[0,g]) -> [G,B,H] ---
  gemm_f16_kernel<128, 128, 64, 64, EPI_L0><<<dim3(G_ * B_ / 128, H_ / 128, 1), 256, 0, stream>>>(
      nullptr, 0, 0, nullptr, 0, 0,
      z1h, R_,
      Wbt, R_, (long long)H_ * R_,
      0, R_ / 32,
      nullptr, 0, bb, H_, y0h,
      xh0, 0, H_, B_);

  f16* cur = xh0;
  f16* nxt = xh1;
  for (int l = 1; l < L_; ++l) {
    // z1[g] = x[g] @ Wa[l,g] + ba[l,g]   (grouped over blockIdx.z)
    gemm_f16_kernel<64, 64, 32, 32, EPI_Z1><<<dim3(B_ / 64, 1, G_), 256, 0, stream>>>(
        cur, H_, (long long)B_ * H_,
        Wat + (size_t)l * G_ * R_ * H_, H_, (long long)R_ * H_,
        nullptr, 0, nullptr, 0, 0,
        H_ / 32, 0,
        ba + (size_t)l * G_ * R_, R_, nullptr, 0, nullptr,
        z1h, (long long)B_ * R_, R_, 0);
    // x_next = elu( x @ W_main[l] + b_main[l] + z1 @ (0.1*Wb[l,g]) + 0.1*bb[l,g] )
    gemm_f16_kernel<128, 128, 64, 64, EPI_MAIN><<<dim3(G_ * B_ / 128, H_ / 128, 1), 256, 0, stream>>>(
        cur, H_, 0,
        Wmt + (size_t)l * H_ * H_, H_, 0,
        z1h, R_,
        Wbt + (size_t)l * G_ * H_ * R_, R_, (long long)H_ * R_,
        H_ / 32, R_ / 32,
        b_main + (size_t)l * H_, 0,
        bb + (size_t)l * G_ * H_, H_, nullptr,
        nxt, 0, H_, B_);
    f16* t = cur; cur = nxt; nxt = t;
  }

  // --- output: logits[b,g,:] = x @ W_out + b_out (fp32, permuted store) ---
  gemm_f16_kernel<128, 128, 64, 64, EPI_OUT><<<dim3(G_ * B_ / 128, A_ / 128, 1), 256, 0, stream>>>(
      cur, H_, 0, Wot, H_, 0,
      nullptr, 0, nullptr, 0, 0,
      H_ / 32, 0,
      b_out, 0, nullptr, 0, nullptr,
      d_out, 0, A_, 0);
}

// Round 3
// 814.602 us; speedup vs baseline: 1.3722x; 1.2386x over previous
//
#include <hip/hip_runtime.h>
#include <cstdint>
#include <cmath>

typedef _Float16 f16;
typedef _Float16 f16x8 __attribute__((ext_vector_type(8)));
typedef float f32x4 __attribute__((ext_vector_type(4)));

#define DEVI static __device__ __forceinline__

constexpr int B_ = 1024, S_ = 512, H_ = 2048, R_ = 64, G_ = 16, L_ = 4, A_ = 256;
constexpr float ADAPT = 0.1f;

// async global->LDS, 16B per lane. Dest is wave-uniform base + lane*16 (HW).
DEVI void gl_lds16(const void* g, void* l) {
  __builtin_amdgcn_global_load_lds((const __attribute__((address_space(1))) void*)g,
                                   (__attribute__((address_space(3))) void*)l,
                                   16, 0, 0);
}

#define BARRIER() asm volatile("s_barrier" ::: "memory")
#define WAITV6()  asm volatile("s_waitcnt vmcnt(6)" ::: "memory")
#define WAITV0()  asm volatile("s_waitcnt vmcnt(0)" ::: "memory")

__global__ void cvt_f16_kernel(const float* __restrict__ src, f16* __restrict__ dst, int n) {
  int i = blockIdx.x * blockDim.x + threadIdx.x;
  if (i < n) dst[i] = (f16)src[i];
}

// src [rows][cols] fp32 -> dst [cols][rows] f16 (×scale), batched over blockIdx.z.
__global__ void transpose_cvt_kernel(const float* __restrict__ src, f16* __restrict__ dst,
                                     int rows, int cols, float scale) {
  src += (size_t)blockIdx.z * rows * cols;
  dst += (size_t)blockIdx.z * rows * cols;
  __shared__ float tile[32][33];
  const int tx = threadIdx.x, ty = threadIdx.y;
  const int r0 = blockIdx.y * 32, c0 = blockIdx.x * 32;
  #pragma unroll
  for (int i = ty; i < 32; i += 8)
    tile[i][tx] = src[(size_t)(r0 + i) * cols + (c0 + tx)];
  __syncthreads();
  #pragma unroll
  for (int i = ty; i < 32; i += 8)
    dst[(size_t)(c0 + i) * rows + (r0 + tx)] = (f16)(tile[tx][i] * scale);
}

// ============================================================================
// 8-phase 256x256 main GEMM (HK-derived template, T1+T2+T3+T4+T5):
//   Out = elu( Aacts[16384,2048] @ Wm^T + b1 + Z1[16384,64] @ (0.1*Wb)^T + 0.1*b2 )
// BK=64, 33 K-tiles (32 main + 1 concat-adapter). 8 waves, 128 KiB LDS dbuf.
// LDS swizzle: byte ^= (row&7)<<4, applied via pre-swizzled global source
// (gl_lds writes linearly) + XOR on ds_read address.
// ============================================================================
__global__ __launch_bounds__(512, 2)
void gemm8_main_kernel(const f16* __restrict__ Aacts,   // [16384][2048]
                      const f16* __restrict__ Wm,       // [2048][2048] W_main^T
                      const f16* __restrict__ Z1,       // [16384][64]
                      const f16* __restrict__ Wb2,      // [G][2048][64] 0.1*Wb^T
                      const float* __restrict__ b1,     // [2048]
                      const float* __restrict__ b2,     // [G][2048]
                      f16* __restrict__ Out) {          // [16384][2048]
  constexpr int NT1 = 32, NT = 33, ST = 4 * NT;
  __shared__ __align__(16) char lds[131072];
  const int tid = threadIdx.x, lane = tid & 63, wid = tid >> 6;
  // XCD-aware swizzle: 512 blocks, 8 XCDs -> each XCD owns one bn column.
  const int swz = (blockIdx.x & 7) * 64 + (blockIdx.x >> 3);
  const int bm0 = (swz & 63) * 256, bn0 = (swz >> 6) * 256;
  const int g = bm0 >> 10;
  const f16* Wbg = Wb2 + (size_t)g * H_ * R_;
  const float* b2g = b2 + (size_t)g * H_;

  // staging source permutation (inverse of read swizzle)
  const int srow8 = lane >> 3;                    // row within 8-row block
  const int scolb = ((lane & 7) ^ srow8) * 16;    // permuted col byte
  // fragment read addressing
  const int fr = lane & 15, fq = lane >> 4;
  const int lof = fr * 128 + ((fq * 16) ^ ((fr & 7) << 4));

  char* Awave = lds + (wid >> 2) * 8192;          // + buf*65536 + Qm*16384 + i*2048
  char* Bwave = lds + 32768 + (wid & 3) * 4096;   // + buf*65536 + Qn*16384 + j*2048

  auto stage = [&](int st) {   // stage half-tile S[st]; S order per tile: A0,B0,A1,B1
    if (st >= ST) return;
    const int tau = st >> 2, kap = st & 3;
    const int isB = kap & 1, half = kap >> 1;
    char* dst = lds + (tau & 1) * 65536 + isB * 32768 + half * 16384 + wid * 2048;
    const int rbase = (isB ? bn0 : bm0) + half * 128;
    #pragma unroll
    for (int j = 0; j < 2; ++j) {
      const int row = rbase + (wid * 2 + j) * 8 + srow8;
      const char* src;
      if (tau < NT1) {
        const char* M = (const char*)(isB ? Wm : Aacts);
        src = M + (size_t)row * 4096 + tau * 128 + scolb;
      } else {  // concat tile: A2 = Z1 (128B rows), B2 = 0.1*Wb^T (128B rows)
        const char* M = (const char*)(isB ? Wbg : Z1);
        src = M + (size_t)row * 128 + scolb;
      }
      gl_lds16(src, dst + j * 1024);
    }
  };

  f32x4 acc[2][2][4][2] = {};   // [Qm][Qn][i][j]
  f16x8 a0[4][2], a1[4][2], b0[2][2], b1f[2][2];

  // prologue: issue 7 half-tiles (tile0 + 3/4 of tile1), retire tile0
  for (int st = 0; st < 7; ++st) stage(st);
  WAITV6();
  BARRIER();

  int st = 7;
  for (int t = 0; t < NT; ++t) {
    char* AB = Awave + (t & 1) * 65536;
    char* BB = Bwave + (t & 1) * 65536;
    // ---- phase 1: quadrant (0,0); reads A0+B0; stages B1(t+1)
    #pragma unroll
    for (int i = 0; i < 4; ++i)
      #pragma unroll
      for (int ks = 0; ks < 2; ++ks)
        a0[i][ks] = *(const f16x8*)(AB + i * 2048 + (lof ^ (ks << 6)));
    #pragma unroll
    for (int j = 0; j < 2; ++j)
      #pragma unroll
      for (int ks = 0; ks < 2; ++ks)
        b0[j][ks] = *(const f16x8*)(BB + j * 2048 + (lof ^ (ks << 6)));
    stage(st++);
    BARRIER();
    __builtin_amdgcn_s_setprio(1);
    #pragma unroll
    for (int i = 0; i < 4; ++i)
      #pragma unroll
      for (int j = 0; j < 2; ++j)
        #pragma unroll
        for (int ks = 0; ks < 2; ++ks)
          acc[0][0][i][j] = __builtin_amdgcn_mfma_f32_16x16x32_f16(a0[i][ks], b0[j][ks], acc[0][0][i][j], 0, 0, 0);
    __builtin_amdgcn_s_setprio(0);
    BARRIER();
    // ---- phase 2: quadrant (0,1); reads B1; stages A0(t+2)
    #pragma unroll
    for (int j = 0; j < 2; ++j)
      #pragma unroll
      for (int ks = 0; ks < 2; ++ks)
        b1f[j][ks] = *(const f16x8*)(BB + 16384 + j * 2048 + (lof ^ (ks << 6)));
    stage(st++);
    BARRIER();
    __builtin_amdgcn_s_setprio(1);
    #pragma unroll
    for (int i = 0; i < 4; ++i)
      #pragma unroll
      for (int j = 0; j < 2; ++j)
        #pragma unroll
        for (int ks = 0; ks < 2; ++ks)
          acc[0][1][i][j] = __builtin_amdgcn_mfma_f32_16x16x32_f16(a0[i][ks], b1f[j][ks], acc[0][1][i][j], 0, 0, 0);
    __builtin_amdgcn_s_setprio(0);
    BARRIER();
    // ---- phase 3: quadrant (1,1); reads A1; stages B0(t+2)
    #pragma unroll
    for (int i = 0; i < 4; ++i)
      #pragma unroll
      for (int ks = 0; ks < 2; ++ks)
        a1[i][ks] = *(const f16x8*)(AB + 16384 + i * 2048 + (lof ^ (ks << 6)));
    stage(st++);
    BARRIER();
    __builtin_amdgcn_s_setprio(1);
    #pragma unroll
    for (int i = 0; i < 4; ++i)
      #pragma unroll
      for (int j = 0; j < 2; ++j)
        #pragma unroll
        for (int ks = 0; ks < 2; ++ks)
          acc[1][1][i][j] = __builtin_amdgcn_mfma_f32_16x16x32_f16(a1[i][ks], b1f[j][ks], acc[1][1][i][j], 0, 0, 0);
    __builtin_amdgcn_s_setprio(0);
    BARRIER();
    // ---- phase 4: quadrant (1,0); no reads; stages A1(t+2); boundary vmcnt
    stage(st++);
    BARRIER();
    __builtin_amdgcn_s_setprio(1);
    #pragma unroll
    for (int i = 0; i < 4; ++i)
      #pragma unroll
      for (int j = 0; j < 2; ++j)
        #pragma unroll
        for (int ks = 0; ks < 2; ++ks)
          acc[1][0][i][j] = __builtin_amdgcn_mfma_f32_16x16x32_f16(a1[i][ks], b0[j][ks], acc[1][0][i][j], 0, 0, 0);
    __builtin_amdgcn_s_setprio(0);
    if (t < NT1 - 1) { WAITV6(); }        // next tile fully landed, 3 ht in flight
    else if (t == NT1 - 1) { WAITV0(); }  // final boundary: drain concat tile
    BARRIER();
  }

  // epilogue: v = acc + b1[col] + 0.1*b2[col]; ELU; f16 store
  #pragma unroll
  for (int Qn = 0; Qn < 2; ++Qn) {
    #pragma unroll
    for (int j = 0; j < 2; ++j) {
      const int col = bn0 + Qn * 128 + (wid & 3) * 32 + j * 16 + fr;
      const float bb1 = b1[col];
      const float bb2 = ADAPT * b2g[col];
      #pragma unroll
      for (int Qm = 0; Qm < 2; ++Qm) {
        #pragma unroll
        for (int i = 0; i < 4; ++i) {
          #pragma unroll
          for (int r = 0; r < 4; ++r) {
            const int row = bm0 + Qm * 128 + (wid >> 2) * 64 + i * 16 + fq * 4 + r;
            float v = acc[Qm][Qn][i][j][r] + bb1 + bb2;
            v = v > 0.f ? v : expm1f(v);
            Out[(size_t)row * H_ + col] = (f16)v;
          }
        }
      }
    }
  }
}

enum { EPI_Z1 = 0, EPI_MAIN = 1, EPI_OUT = 2, EPI_L0 = 3 };

// m97-structure GEMM for the small/odd-shaped ops (unchanged from round 2).
template <int BM, int BN, int WM, int WN, int EPI>
__global__ __launch_bounds__((BM / WM) * (BN / WN) * 64)
void gemm_f16_kernel(const f16* __restrict__ A, long long lda, long long Az,
                     const f16* __restrict__ Bw, long long ldb, long long Bz,
                     const f16* __restrict__ A2, long long lda2,
                     const f16* __restrict__ B2w, long long ldb2, long long B2z,
                     int NT1, int NT2,
                     const float* __restrict__ bias1, long long b1z,
                     const float* __restrict__ bias2, long long b2z,
                     const f16* __restrict__ addmat,
                     void* __restrict__ outp, long long out_z, long long ldo,
                     int rows_per_group) {
  constexpr int NW = (BM / WM) * (BN / WN);
  constexpr int FM = WM / 16, FN = WN / 16;
  constexpr int RA = BM / (NW * 16), RB = BN / (NW * 16);
  const int tid = threadIdx.x, lane = tid & 63, wid = tid >> 6;
  const int bm0 = blockIdx.x * BM, bn0 = blockIdx.y * BN;
  const int z = blockIdx.z;
  const int gidx = (rows_per_group > 0) ? (bm0 / rows_per_group) : 0;

  __shared__ __align__(16) f16 As[BM * 32];
  __shared__ __align__(16) f16 Bs[BN * 32];

  const int wm0 = (wid / (BN / WN)) * WM;
  const int wn0 = (wid % (BN / WN)) * WN;
  const int srow = wid * 16 + (lane >> 2);
  const int scol = (lane & 3) * 8;
  const int fr = lane & 15, fq = lane >> 4;

  f32x4 acc[FM][FN] = {};

  const f16* arp = &As[(wm0 + fr) * 32 + fq * 8];
  const f16* brp = &Bs[(wn0 + fr) * 32 + fq * 8];
  auto compute = [&]() {
    f16x8 af[FM], bf[FN];
    #pragma unroll
    for (int i = 0; i < FM; ++i) af[i] = *(const f16x8*)(arp + i * 16 * 32);
    #pragma unroll
    for (int j = 0; j < FN; ++j) bf[j] = *(const f16x8*)(brp + j * 16 * 32);
    #pragma unroll
    for (int i = 0; i < FM; ++i)
      #pragma unroll
      for (int j = 0; j < FN; ++j)
        acc[i][j] = __builtin_amdgcn_mfma_f32_16x16x32_f16(af[i], bf[j], acc[i][j], 0, 0, 0);
  };

  if (NT1 > 0) {
    const f16* pa = A + (long long)z * Az + (long long)(bm0 + srow) * lda + scol;
    const f16* pb = Bw + (long long)z * Bz + (long long)(bn0 + srow) * ldb + scol;
    const long long stA = (long long)(NW * 16) * lda;
    const long long stB = (long long)(NW * 16) * ldb;
    for (int kt = 0; kt < NT1; ++kt) {
      #pragma unroll
      for (int r = 0; r < RA; ++r) gl_lds16(pa + r * stA, &As[(r * NW + wid) * 512]);
      #pragma unroll
      for (int r = 0; r < RB; ++r) gl_lds16(pb + r * stB, &Bs[(r * NW + wid) * 512]);
      pa += 32; pb += 32;
      __syncthreads();
      compute();
      __syncthreads();
    }
  }
  if (NT2 > 0) {
    const f16* pa = A2 + (long long)(bm0 + srow) * lda2 + scol;
    const f16* pb = B2w + (long long)gidx * B2z + (long long)(bn0 + srow) * ldb2 + scol;
    const long long stA = (long long)(NW * 16) * lda2;
    const long long stB = (long long)(NW * 16) * ldb2;
    for (int kt = 0; kt < NT2; ++kt) {
      #pragma unroll
      for (int r = 0; r < RA; ++r) gl_lds16(pa + r * stA, &As[(r * NW + wid) * 512]);
      #pragma unroll
      for (int r = 0; r < RB; ++r) gl_lds16(pb + r * stB, &Bs[(r * NW + wid) * 512]);
      pa += 32; pb += 32;
      __syncthreads();
      compute();
      __syncthreads();
    }
  }

  const float* b1p = bias1 ? bias1 + (long long)z * b1z : nullptr;
  const float* b2p = bias2 ? bias2 + (long long)gidx * b2z : nullptr;
  #pragma unroll
  for (int i = 0; i < FM; ++i) {
    #pragma unroll
    for (int j = 0; j < FN; ++j) {
      const int col = bn0 + wn0 + j * 16 + fr;
      const float b1 = b1p ? b1p[col] : 0.f;
      const float b2v = b2p ? ADAPT * b2p[col] : 0.f;
      #pragma unroll
      for (int r = 0; r < 4; ++r) {
        const int row = bm0 + wm0 + i * 16 + fq * 4 + r;
        float v = acc[i][j][r] + b1 + b2v;
        if constexpr (EPI == EPI_MAIN) {
          v = v > 0.f ? v : expm1f(v);
          ((f16*)outp)[(long long)row * ldo + col] = (f16)v;
        } else if constexpr (EPI == EPI_L0) {
          v += (float)addmat[(long long)(row & (B_ - 1)) * H_ + col];
          v = v > 0.f ? v : expm1f(v);
          ((f16*)outp)[(long long)row * ldo + col] = (f16)v;
        } else if constexpr (EPI == EPI_Z1) {
          ((f16*)outp)[(long long)z * out_z + (long long)row * ldo + col] = (f16)v;
        } else {
          const int g = row >> 10, b = row & 1023;
          ((float*)outp)[((long long)b * G_ + g) * A_ + col] = v;
        }
      }
    }
  }
}

extern "C" void kernel_launch(void* const* d_in, const int* in_sizes, int n_in,
                              void* d_out, int out_size, void* d_ws, size_t ws_size,
                              hipStream_t stream) {
  const float* s      = (const float*)d_in[0];
  const float* W_in   = (const float*)d_in[1];
  const float* b_in   = (const float*)d_in[2];
  const float* W_main = (const float*)d_in[3];
  const float* b_main = (const float*)d_in[4];
  const float* Wa     = (const float*)d_in[5];
  const float* ba     = (const float*)d_in[6];
  const float* Wb     = (const float*)d_in[7];
  const float* bb     = (const float*)d_in[8];
  const float* W_out  = (const float*)d_in[9];
  const float* b_out  = (const float*)d_in[10];

  char* ws = (char*)d_ws;
  size_t off = 0;
  auto alloc = [&](size_t bytes) -> void* {
    void* p = ws + off;
    off += (bytes + 255) & ~(size_t)255;
    return p;
  };
  f16* sh   = (f16*)alloc((size_t)B_ * S_ * 2);
  f16* Wint = (f16*)alloc((size_t)H_ * S_ * 2);
  f16* Wmt  = (f16*)alloc((size_t)L_ * H_ * H_ * 2);
  f16* Wat  = (f16*)alloc((size_t)L_ * G_ * R_ * H_ * 2);
  f16* Wbt  = (f16*)alloc((size_t)L_ * G_ * H_ * R_ * 2);
  f16* Wot  = (f16*)alloc((size_t)A_ * H_ * 2);
  f16* xh0  = (f16*)alloc((size_t)G_ * B_ * H_ * 2);
  f16* xh1  = (f16*)alloc((size_t)G_ * B_ * H_ * 2);
  f16* z1h  = (f16*)alloc((size_t)G_ * B_ * R_ * 2);
  f16* x0h  = xh1;                     // aliases: dead before xh1 first written
  f16* y0h  = xh1 + (size_t)B_ * H_;

  cvt_f16_kernel<<<(B_ * S_ + 255) / 256, 256, 0, stream>>>(s, sh, B_ * S_);
  dim3 tb(32, 8);
  transpose_cvt_kernel<<<dim3(H_ / 32, S_ / 32, 1),   tb, 0, stream>>>(W_in,   Wint, S_, H_, 1.f);
  transpose_cvt_kernel<<<dim3(H_ / 32, H_ / 32, L_),  tb, 0, stream>>>(W_main, Wmt,  H_, H_, 1.f);
  transpose_cvt_kernel<<<dim3(R_ / 32, H_ / 32, L_ * G_), tb, 0, stream>>>(Wa, Wat, H_, R_, 1.f);
  transpose_cvt_kernel<<<dim3(H_ / 32, R_ / 32, L_ * G_), tb, 0, stream>>>(Wb, Wbt, R_, H_, ADAPT);
  transpose_cvt_kernel<<<dim3(A_ / 32, H_ / 32, 1),   tb, 0, stream>>>(W_out,  Wot,  H_, A_, 1.f);

  // x0 = s @ W_in + b_in  [B, H]
  gemm_f16_kernel<64, 128, 32, 64, EPI_Z1><<<dim3(B_ / 64, H_ / 128, 1), 256, 0, stream>>>(
      sh, S_, 0, Wint, S_, 0, nullptr, 0, nullptr, 0, 0,
      S_ / 32, 0, b_in, 0, nullptr, 0, nullptr, x0h, 0, H_, 0);

  // y0 = x0 @ W_main[0] + b_main[0]  [B, H] (group-invariant: 1/16 the work)
  gemm_f16_kernel<64, 128, 32, 64, EPI_Z1><<<dim3(B_ / 64, H_ / 128, 1), 256, 0, stream>>>(
      x0h, H_, 0, Wmt, H_, 0, nullptr, 0, nullptr, 0, 0,
      H_ / 32, 0, b_main, 0, nullptr, 0, nullptr, y0h, 0, H_, 0);

  // layer-0 z1[g] = x0 @ Wa[0,g] + ba[0,g]
  gemm_f16_kernel<64, 64, 32, 32, EPI_Z1><<<dim3(B_ / 64, 1, G_), 256, 0, stream>>>(
      x0h, H_, 0, Wat, H_, (long long)R_ * H_, nullptr, 0, nullptr, 0, 0,
      H_ / 32, 0, ba, R_, nullptr, 0, nullptr, z1h, (long long)B_ * R_, R_, 0);

  // layer-0 combine: x1 = elu(y0 + z1 @ (0.1*Wb[0,g]) + 0.1*bb[0,g]) -> [G,B,H]
  gemm_f16_kernel<128, 128, 64, 64, EPI_L0><<<dim3(G_ * B_ / 128, H_ / 128, 1), 256, 0, stream>>>(
      nullptr, 0, 0, nullptr, 0, 0, z1h, R_, Wbt, R_, (long long)H_ * R_,
      0, R_ / 32, nullptr, 0, bb, H_, y0h, xh0, 0, H_, B_);

  f16* cur = xh0;
  f16* nxt = xh1;
  for (int l = 1; l < L_; ++l) {
    gemm_f16_kernel<64, 64, 32, 32, EPI_Z1><<<dim3(B_ / 64, 1, G_), 256, 0, stream>>>(
        cur, H_, (long long)B_ * H_,
        Wat + (size_t)l * G_ * R_ * H_, H_, (long long)R_ * H_,
        nullptr, 0, nullptr, 0, 0,
        H_ / 32, 0,
        ba + (size_t)l * G_ * R_, R_, nullptr, 0, nullptr,
        z1h, (long long)B_ * R_, R_, 0);
    // 8-phase 256^2 main GEMM with fused adapter concat-K and ELU epilogue
    gemm8_main_kernel<<<512, 512, 0, stream>>>(
        cur, Wmt + (size_t)l * H_ * H_, z1h, Wbt + (size_t)l * G_ * H_ * R_,
        b_main + (size_t)l * H_, bb + (size_t)l * G_ * H_, nxt);
    f16* t = cur; cur = nxt; nxt = t;
  }

  gemm_f16_kernel<128, 128, 64, 64, EPI_OUT><<<dim3(G_ * B_ / 128, A_ / 128, 1), 256, 0, stream>>>(
      cur, H_, 0, Wot, H_, 0, nullptr, 0, nullptr, 0, 0,
      H_ / 32, 0, b_out, 0, nullptr, 0, nullptr, d_out, 0, A_, 0);
}

// Round 4
// 798.414 us; speedup vs baseline: 1.4000x; 1.0203x over previous
//
#include <hip/hip_runtime.h>
#include <cstdint>
#include <cmath>

typedef _Float16 f16;
typedef _Float16 f16x8 __attribute__((ext_vector_type(8)));
typedef float f32x4 __attribute__((ext_vector_type(4)));

#define DEVI static __device__ __forceinline__

constexpr int B_ = 1024, S_ = 512, H_ = 2048, R_ = 64, G_ = 16, L_ = 4, A_ = 256;
constexpr float ADAPT = 0.1f;

// async global->LDS, 16B per lane. Dest is wave-uniform base + lane*16 (HW).
DEVI void gl_lds16(const void* g, void* l) {
  __builtin_amdgcn_global_load_lds((const __attribute__((address_space(1))) void*)g,
                                   (__attribute__((address_space(3))) void*)l,
                                   16, 0, 0);
}

__global__ void cvt_f16_kernel(const float* __restrict__ src, f16* __restrict__ dst, int n) {
  int i = blockIdx.x * blockDim.x + threadIdx.x;
  if (i < n) dst[i] = (f16)src[i];
}

// src [rows][cols] fp32 -> dst [cols][rows] f16 (×scale), batched over blockIdx.z.
__global__ void transpose_cvt_kernel(const float* __restrict__ src, f16* __restrict__ dst,
                                     int rows, int cols, float scale) {
  src += (size_t)blockIdx.z * rows * cols;
  dst += (size_t)blockIdx.z * rows * cols;
  __shared__ float tile[32][33];
  const int tx = threadIdx.x, ty = threadIdx.y;
  const int r0 = blockIdx.y * 32, c0 = blockIdx.x * 32;
  #pragma unroll
  for (int i = ty; i < 32; i += 8)
    tile[i][tx] = src[(size_t)(r0 + i) * cols + (c0 + tx)];
  __syncthreads();
  #pragma unroll
  for (int i = ty; i < 32; i += 8)
    dst[(size_t)(c0 + i) * rows + (r0 + tx)] = (f16)(tile[tx][i] * scale);
}

// ============================================================================
// 8-phase 256x256 main GEMM (T1+T2+T3+T4+T5), builtin-barrier spelling,
// branch-free rolled steady-state with incremental staging offsets.
//   Out = elu( Aacts[16384,2048] @ Wm^T + b1 + Z1[16384,64] @ (0.1*Wb)^T + 0.1*b2 )
// ============================================================================

// MFMA quadrant: 16 x mfma_16x16x32 accumulating acc[QM][QN]
#define MQ(QM, QN, AF, BF)                                                   \
  _Pragma("unroll") for (int i = 0; i < 4; ++i)                              \
  _Pragma("unroll") for (int j = 0; j < 2; ++j)                              \
  _Pragma("unroll") for (int k = 0; k < 2; ++k)                              \
    acc[QM][QN][i][j] = __builtin_amdgcn_mfma_f32_16x16x32_f16(              \
        AF[i][k], BF[j][k], acc[QM][QN][i][j], 0, 0, 0)

// stage one half-tile from main region (row stride 4096 B), advance
#define STGM(BASE, OFF, DST) do {                                            \
    gl_lds16(BASE + OFF, &lds[DST]);                                         \
    gl_lds16(BASE + OFF + 32768, &lds[DST + 1024]);                          \
    OFF += 128; DST ^= 65536; } while (0)
// stage one half-tile from concat region (row stride 128 B)
#define STGC(BASE, OFF, DST) do {                                            \
    gl_lds16(BASE + OFF, &lds[DST]);                                         \
    gl_lds16(BASE + OFF + 1024, &lds[DST + 1024]);                           \
    DST ^= 65536; } while (0)
#define NOSTG ((void)0)
#define WV6 asm volatile("s_waitcnt vmcnt(6)")
#define WV0 asm volatile("s_waitcnt vmcnt(0)")
#define NOW ((void)0)

#define TILE_BODY(S1, S2, S3, S4, BW) do {                                   \
    f16x8 a0[4][2], a1[4][2], b0[2][2], b1v[2][2];                           \
    _Pragma("unroll") for (int i = 0; i < 4; ++i) {                          \
      a0[i][0] = *(const f16x8*)&lds[cab + i * 2048 + lof0];                 \
      a0[i][1] = *(const f16x8*)&lds[cab + i * 2048 + lof1]; }               \
    _Pragma("unroll") for (int j = 0; j < 2; ++j) {                          \
      b0[j][0] = *(const f16x8*)&lds[cbb + j * 2048 + lof0];                 \
      b0[j][1] = *(const f16x8*)&lds[cbb + j * 2048 + lof1]; }               \
    S1;                                                                      \
    __builtin_amdgcn_s_barrier();                                            \
    __builtin_amdgcn_s_setprio(1);                                           \
    MQ(0, 0, a0, b0);                                                        \
    __builtin_amdgcn_s_setprio(0);                                           \
    __builtin_amdgcn_s_barrier();                                            \
    _Pragma("unroll") for (int j = 0; j < 2; ++j) {                          \
      b1v[j][0] = *(const f16x8*)&lds[cbb + 16384 + j * 2048 + lof0];        \
      b1v[j][1] = *(const f16x8*)&lds[cbb + 16384 + j * 2048 + lof1]; }      \
    S2;                                                                      \
    __builtin_amdgcn_s_barrier();                                            \
    __builtin_amdgcn_s_setprio(1);                                           \
    MQ(0, 1, a0, b1v);                                                       \
    __builtin_amdgcn_s_setprio(0);                                           \
    __builtin_amdgcn_s_barrier();                                            \
    _Pragma("unroll") for (int i = 0; i < 4; ++i) {                          \
      a1[i][0] = *(const f16x8*)&lds[cab + 16384 + i * 2048 + lof0];         \
      a1[i][1] = *(const f16x8*)&lds[cab + 16384 + i * 2048 + lof1]; }       \
    S3;                                                                      \
    __builtin_amdgcn_s_barrier();                                            \
    __builtin_amdgcn_s_setprio(1);                                           \
    MQ(1, 1, a1, b1v);                                                       \
    __builtin_amdgcn_s_setprio(0);                                           \
    __builtin_amdgcn_s_barrier();                                            \
    S4;                                                                      \
    __builtin_amdgcn_s_barrier();                                            \
    __builtin_amdgcn_s_setprio(1);                                           \
    MQ(1, 0, a1, b0);                                                        \
    __builtin_amdgcn_s_setprio(0);                                           \
    BW;                                                                      \
    __builtin_amdgcn_s_barrier();                                            \
    cab ^= 65536; cbb ^= 65536;                                              \
  } while (0)

__global__ __launch_bounds__(512, 2)
void gemm8_main_kernel(const f16* __restrict__ Aacts,   // [16384][2048]
                      const f16* __restrict__ Wm,       // [2048][2048] W_main^T
                      const f16* __restrict__ Z1,       // [16384][64]
                      const f16* __restrict__ Wb2,      // [G][2048][64] 0.1*Wb^T
                      const float* __restrict__ b1,     // [2048]
                      const float* __restrict__ b2,     // [G][2048]
                      f16* __restrict__ Out) {          // [16384][2048]
  __shared__ __align__(16) char lds[131072];
  const int tid = threadIdx.x, lane = tid & 63, wid = tid >> 6;
  // XCD-aware swizzle: 512 blocks, 8 XCDs -> each XCD owns one bn column.
  const int swz = (blockIdx.x & 7) * 64 + (blockIdx.x >> 3);
  const int bm0 = (swz & 63) * 256, bn0 = (swz >> 6) * 256;
  const int g = bm0 >> 10;
  const char* GA = (const char*)Aacts;
  const char* GB = (const char*)Wm;
  const char* GZ = (const char*)Z1;
  const char* GW2 = (const char*)(Wb2 + (size_t)g * H_ * R_);
  const float* b2g = b2 + (size_t)g * H_;

  // staging source permutation (inverse of read swizzle)
  const int srow8 = lane >> 3;                    // row within 8-row block
  const int scolb = ((lane & 7) ^ srow8) * 16;    // permuted col byte
  // fragment read addressing
  const int fr = lane & 15, fq = lane >> 4;
  const uint32_t lof0 = fr * 128 + ((fq * 16) ^ ((fr & 7) << 4));
  const uint32_t lof1 = lof0 ^ 64;

  // staging rows (per-thread invariant)
  const uint32_t rA0 = bm0 + wid * 16 + srow8;
  const uint32_t rB0 = bn0 + wid * 16 + srow8;
  // main-region source byte offsets (advance +128 per staged tile)
  uint32_t oA0 = rA0 * 4096 + scolb;
  uint32_t oA1 = oA0 + 128 * 4096;
  uint32_t oB0 = rB0 * 4096 + scolb;
  uint32_t oB1 = oB0 + 128 * 4096;
  // LDS dest offsets per half-tile kind (parity toggles per use)
  uint32_t dA0 = wid * 2048;
  uint32_t dA1 = 16384 + wid * 2048;
  uint32_t dB0 = 32768 + wid * 2048;
  uint32_t dB1 = 49152 + wid * 2048;
  // compute-buffer bases (parity toggles per tile)
  uint32_t cab = (wid >> 2) * 8192;
  uint32_t cbb = 32768 + (wid & 3) * 4096;

  f32x4 acc[2][2][4][2] = {};   // [Qm][Qn][i][j]

  // prologue: tile0 (A0,B0,A1,B1) + tile1 (A0,B0,A1) = 14 loads; retire tile0
  STGM(GA, oA0, dA0);
  STGM(GB, oB0, dB0);
  STGM(GA, oA1, dA1);
  STGM(GB, oB1, dB1);
  STGM(GA, oA0, dA0);
  STGM(GB, oB0, dB0);
  STGM(GA, oA1, dA1);
  WV6;
  __builtin_amdgcn_s_barrier();

  // steady state: tiles 0..29, all staging regular (stages tiles <= 31)
  for (int t = 0; t < 30; ++t)
    TILE_BODY(STGM(GB, oB1, dB1), STGM(GA, oA0, dA0),
              STGM(GB, oB0, dB0), STGM(GA, oA1, dA1), WV6);

  // t=30: B1(31) regular; A0/B0/A1 of tile 32 = concat (Z1 / 0.1*Wb^T, 128B rows)
  {
    uint32_t oA0c = rA0 * 128 + scolb;
    uint32_t oA1c = oA0c + 128 * 128;
    uint32_t oB0c = rB0 * 128 + scolb;
    uint32_t oB1c = oB0c + 128 * 128;
    TILE_BODY(STGM(GB, oB1, dB1), STGC(GZ, oA0c, dA0),
              STGC(GW2, oB0c, dB0), STGC(GZ, oA1c, dA1), WV6);
    // t=31: B1(32) concat; nothing else; drain all
    TILE_BODY(STGC(GW2, oB1c, dB1), NOSTG, NOSTG, NOSTG, WV0);
  }
  // t=32: concat tile compute, no staging
  TILE_BODY(NOSTG, NOSTG, NOSTG, NOSTG, NOW);

  // epilogue: v = acc + b1[col] + 0.1*b2[col]; ELU; f16 store
  #pragma unroll
  for (int Qn = 0; Qn < 2; ++Qn) {
    #pragma unroll
    for (int j = 0; j < 2; ++j) {
      const int col = bn0 + Qn * 128 + (wid & 3) * 32 + j * 16 + fr;
      const float bb1 = b1[col];
      const float bb2 = ADAPT * b2g[col];
      #pragma unroll
      for (int Qm = 0; Qm < 2; ++Qm) {
        #pragma unroll
        for (int i = 0; i < 4; ++i) {
          #pragma unroll
          for (int r = 0; r < 4; ++r) {
            const int row = bm0 + Qm * 128 + (wid >> 2) * 64 + i * 16 + fq * 4 + r;
            float v = acc[Qm][Qn][i][j][r] + bb1 + bb2;
            v = v > 0.f ? v : expm1f(v);
            Out[(size_t)row * H_ + col] = (f16)v;
          }
        }
      }
    }
  }
}

enum { EPI_Z1 = 0, EPI_MAIN = 1, EPI_OUT = 2, EPI_L0 = 3 };

// m97-structure GEMM for the small/odd-shaped ops.
template <int BM, int BN, int WM, int WN, int EPI>
__global__ __launch_bounds__((BM / WM) * (BN / WN) * 64)
void gemm_f16_kernel(const f16* __restrict__ A, long long lda, long long Az,
                     const f16* __restrict__ Bw, long long ldb, long long Bz,
                     const f16* __restrict__ A2, long long lda2,
                     const f16* __restrict__ B2w, long long ldb2, long long B2z,
                     int NT1, int NT2,
                     const float* __restrict__ bias1, long long b1z,
                     const float* __restrict__ bias2, long long b2z,
                     const f16* __restrict__ addmat,
                     void* __restrict__ outp, long long out_z, long long ldo,
                     int rows_per_group) {
  constexpr int NW = (BM / WM) * (BN / WN);
  constexpr int FM = WM / 16, FN = WN / 16;
  constexpr int RA = BM / (NW * 16), RB = BN / (NW * 16);
  const int tid = threadIdx.x, lane = tid & 63, wid = tid >> 6;
  const int bm0 = blockIdx.x * BM, bn0 = blockIdx.y * BN;
  const int z = blockIdx.z;
  const int gidx = (rows_per_group > 0) ? (bm0 / rows_per_group) : 0;

  __shared__ __align__(16) f16 As[BM * 32];
  __shared__ __align__(16) f16 Bs[BN * 32];

  const int wm0 = (wid / (BN / WN)) * WM;
  const int wn0 = (wid % (BN / WN)) * WN;
  const int srow = wid * 16 + (lane >> 2);
  const int scol = (lane & 3) * 8;
  const int fr = lane & 15, fq = lane >> 4;

  f32x4 acc[FM][FN] = {};

  const f16* arp = &As[(wm0 + fr) * 32 + fq * 8];
  const f16* brp = &Bs[(wn0 + fr) * 32 + fq * 8];
  auto compute = [&]() {
    f16x8 af[FM], bf[FN];
    #pragma unroll
    for (int i = 0; i < FM; ++i) af[i] = *(const f16x8*)(arp + i * 16 * 32);
    #pragma unroll
    for (int j = 0; j < FN; ++j) bf[j] = *(const f16x8*)(brp + j * 16 * 32);
    #pragma unroll
    for (int i = 0; i < FM; ++i)
      #pragma unroll
      for (int j = 0; j < FN; ++j)
        acc[i][j] = __builtin_amdgcn_mfma_f32_16x16x32_f16(af[i], bf[j], acc[i][j], 0, 0, 0);
  };

  if (NT1 > 0) {
    const f16* pa = A + (long long)z * Az + (long long)(bm0 + srow) * lda + scol;
    const f16* pb = Bw + (long long)z * Bz + (long long)(bn0 + srow) * ldb + scol;
    const long long stA = (long long)(NW * 16) * lda;
    const long long stB = (long long)(NW * 16) * ldb;
    for (int kt = 0; kt < NT1; ++kt) {
      #pragma unroll
      for (int r = 0; r < RA; ++r) gl_lds16(pa + r * stA, &As[(r * NW + wid) * 512]);
      #pragma unroll
      for (int r = 0; r < RB; ++r) gl_lds16(pb + r * stB, &Bs[(r * NW + wid) * 512]);
      pa += 32; pb += 32;
      __syncthreads();
      compute();
      __syncthreads();
    }
  }
  if (NT2 > 0) {
    const f16* pa = A2 + (long long)(bm0 + srow) * lda2 + scol;
    const f16* pb = B2w + (long long)gidx * B2z + (long long)(bn0 + srow) * ldb2 + scol;
    const long long stA = (long long)(NW * 16) * lda2;
    const long long stB = (long long)(NW * 16) * ldb2;
    for (int kt = 0; kt < NT2; ++kt) {
      #pragma unroll
      for (int r = 0; r < RA; ++r) gl_lds16(pa + r * stA, &As[(r * NW + wid) * 512]);
      #pragma unroll
      for (int r = 0; r < RB; ++r) gl_lds16(pb + r * stB, &Bs[(r * NW + wid) * 512]);
      pa += 32; pb += 32;
      __syncthreads();
      compute();
      __syncthreads();
    }
  }

  const float* b1p = bias1 ? bias1 + (long long)z * b1z : nullptr;
  const float* b2p = bias2 ? bias2 + (long long)gidx * b2z : nullptr;
  #pragma unroll
  for (int i = 0; i < FM; ++i) {
    #pragma unroll
    for (int j = 0; j < FN; ++j) {
      const int col = bn0 + wn0 + j * 16 + fr;
      const float b1 = b1p ? b1p[col] : 0.f;
      const float b2v = b2p ? ADAPT * b2p[col] : 0.f;
      #pragma unroll
      for (int r = 0; r < 4; ++r) {
        const int row = bm0 + wm0 + i * 16 + fq * 4 + r;
        float v = acc[i][j][r] + b1 + b2v;
        if constexpr (EPI == EPI_MAIN) {
          v = v > 0.f ? v : expm1f(v);
          ((f16*)outp)[(long long)row * ldo + col] = (f16)v;
        } else if constexpr (EPI == EPI_L0) {
          v += (float)addmat[(long long)(row & (B_ - 1)) * H_ + col];
          v = v > 0.f ? v : expm1f(v);
          ((f16*)outp)[(long long)row * ldo + col] = (f16)v;
        } else if constexpr (EPI == EPI_Z1) {
          ((f16*)outp)[(long long)z * out_z + (long long)row * ldo + col] = (f16)v;
        } else {
          const int g = row >> 10, b = row & 1023;
          ((float*)outp)[((long long)b * G_ + g) * A_ + col] = v;
        }
      }
    }
  }
}

extern "C" void kernel_launch(void* const* d_in, const int* in_sizes, int n_in,
                              void* d_out, int out_size, void* d_ws, size_t ws_size,
                              hipStream_t stream) {
  const float* s      = (const float*)d_in[0];
  const float* W_in   = (const float*)d_in[1];
  const float* b_in   = (const float*)d_in[2];
  const float* W_main = (const float*)d_in[3];
  const float* b_main = (const float*)d_in[4];
  const float* Wa     = (const float*)d_in[5];
  const float* ba     = (const float*)d_in[6];
  const float* Wb     = (const float*)d_in[7];
  const float* bb     = (const float*)d_in[8];
  const float* W_out  = (const float*)d_in[9];
  const float* b_out  = (const float*)d_in[10];

  char* ws = (char*)d_ws;
  size_t off = 0;
  auto alloc = [&](size_t bytes) -> void* {
    void* p = ws + off;
    off += (bytes + 255) & ~(size_t)255;
    return p;
  };
  f16* sh   = (f16*)alloc((size_t)B_ * S_ * 2);
  f16* Wint = (f16*)alloc((size_t)H_ * S_ * 2);
  f16* Wmt  = (f16*)alloc((size_t)L_ * H_ * H_ * 2);
  f16* Wat  = (f16*)alloc((size_t)L_ * G_ * R_ * H_ * 2);
  f16* Wbt  = (f16*)alloc((size_t)L_ * G_ * H_ * R_ * 2);
  f16* Wot  = (f16*)alloc((size_t)A_ * H_ * 2);
  f16* xh0  = (f16*)alloc((size_t)G_ * B_ * H_ * 2);
  f16* xh1  = (f16*)alloc((size_t)G_ * B_ * H_ * 2);
  f16* z1h  = (f16*)alloc((size_t)G_ * B_ * R_ * 2);
  f16* x0h  = xh1;                     // aliases: dead before xh1 first written
  f16* y0h  = xh1 + (size_t)B_ * H_;

  cvt_f16_kernel<<<(B_ * S_ + 255) / 256, 256, 0, stream>>>(s, sh, B_ * S_);
  dim3 tb(32, 8);
  transpose_cvt_kernel<<<dim3(H_ / 32, S_ / 32, 1),   tb, 0, stream>>>(W_in,   Wint, S_, H_, 1.f);
  transpose_cvt_kernel<<<dim3(H_ / 32, H_ / 32, L_),  tb, 0, stream>>>(W_main, Wmt,  H_, H_, 1.f);
  transpose_cvt_kernel<<<dim3(R_ / 32, H_ / 32, L_ * G_), tb, 0, stream>>>(Wa, Wat, H_, R_, 1.f);
  transpose_cvt_kernel<<<dim3(H_ / 32, R_ / 32, L_ * G_), tb, 0, stream>>>(Wb, Wbt, R_, H_, ADAPT);
  transpose_cvt_kernel<<<dim3(A_ / 32, H_ / 32, 1),   tb, 0, stream>>>(W_out,  Wot,  H_, A_, 1.f);

  // x0 = s @ W_in + b_in  [B, H]
  gemm_f16_kernel<64, 128, 32, 64, EPI_Z1><<<dim3(B_ / 64, H_ / 128, 1), 256, 0, stream>>>(
      sh, S_, 0, Wint, S_, 0, nullptr, 0, nullptr, 0, 0,
      S_ / 32, 0, b_in, 0, nullptr, 0, nullptr, x0h, 0, H_, 0);

  // y0 = x0 @ W_main[0] + b_main[0]  [B, H] (group-invariant: 1/16 the work)
  gemm_f16_kernel<64, 128, 32, 64, EPI_Z1><<<dim3(B_ / 64, H_ / 128, 1), 256, 0, stream>>>(
      x0h, H_, 0, Wmt, H_, 0, nullptr, 0, nullptr, 0, 0,
      H_ / 32, 0, b_main, 0, nullptr, 0, nullptr, y0h, 0, H_, 0);

  // layer-0 z1[g] = x0 @ Wa[0,g] + ba[0,g]
  gemm_f16_kernel<64, 64, 32, 32, EPI_Z1><<<dim3(B_ / 64, 1, G_), 256, 0, stream>>>(
      x0h, H_, 0, Wat, H_, (long long)R_ * H_, nullptr, 0, nullptr, 0, 0,
      H_ / 32, 0, ba, R_, nullptr, 0, nullptr, z1h, (long long)B_ * R_, R_, 0);

  // layer-0 combine: x1 = elu(y0 + z1 @ (0.1*Wb[0,g]) + 0.1*bb[0,g]) -> [G,B,H]
  gemm_f16_kernel<128, 128, 64, 64, EPI_L0><<<dim3(G_ * B_ / 128, H_ / 128, 1), 256, 0, stream>>>(
      nullptr, 0, 0, nullptr, 0, 0, z1h, R_, Wbt, R_, (long long)H_ * R_,
      0, R_ / 32, nullptr, 0, bb, H_, y0h, xh0, 0, H_, B_);

  f16* cur = xh0;
  f16* nxt = xh1;
  for (int l = 1; l < L_; ++l) {
    gemm_f16_kernel<64, 64, 32, 32, EPI_Z1><<<dim3(B_ / 64, 1, G_), 256, 0, stream>>>(
        cur, H_, (long long)B_ * H_,
        Wat + (size_t)l * G_ * R_ * H_, H_, (long long)R_ * H_,
        nullptr, 0, nullptr, 0, 0,
        H_ / 32, 0,
        ba + (size_t)l * G_ * R_, R_, nullptr, 0, nullptr,
        z1h, (long long)B_ * R_, R_, 0);
    // 8-phase 256^2 main GEMM with fused adapter concat-K and ELU epilogue
    gemm8_main_kernel<<<512, 512, 0, stream>>>(
        cur, Wmt + (size_t)l * H_ * H_, z1h, Wbt + (size_t)l * G_ * H_ * R_,
        b_main + (size_t)l * H_, bb + (size_t)l * G_ * H_, nxt);
    f16* t = cur; cur = nxt; nxt = t;
  }

  gemm_f16_kernel<128, 128, 64, 64, EPI_OUT><<<dim3(G_ * B_ / 128, A_ / 128, 1), 256, 0, stream>>>(
      cur, H_, 0, Wot, H_, 0, nullptr, 0, nullptr, 0, 0,
      H_ / 32, 0, b_out, 0, nullptr, 0, nullptr, d_out, 0, A_, 0);
}